// Round 11
// baseline (44900.827 us; speedup 1.0000x reference)
//
#include <hip/hip_runtime.h>
#include <math.h>

#define IN_SIZE 96
#define HID 128
#define H3 384
#define LIN_IN 32

// ---------------------------------------------------------------------------
// Kernel A (parallel): igates[t][j] = dot(input_GRU[t,:], w_ih[j,:]) + b_ih[j]
// ---------------------------------------------------------------------------
__global__ __launch_bounds__(384, 2)
void igates_kernel(const float* __restrict__ x, const float* __restrict__ w_ih,
                   const float* __restrict__ b_ih, float* __restrict__ ig, int T)
{
    const int TT = 16;
    int t0 = blockIdx.x * TT;
    int j = threadIdx.x; // 0..383
    __shared__ __align__(16) float xs[TT * IN_SIZE]; // 6 KB
    for (int idx = j; idx < TT * IN_SIZE; idx += H3)
        xs[idx] = x[(size_t)t0 * IN_SIZE + idx];
    __syncthreads();

    float acc[TT];
    float b = b_ih[j];
#pragma unroll
    for (int tt = 0; tt < TT; tt++) acc[tt] = b;

    const float4* w4 = (const float4*)(w_ih + (size_t)j * IN_SIZE);
#pragma unroll
    for (int k = 0; k < IN_SIZE / 4; k++) {
        float4 wv = w4[k];
#pragma unroll
        for (int tt = 0; tt < TT; tt++) {
            const float4* xv4 = (const float4*)(xs + tt * IN_SIZE);
            float4 xv = xv4[k];
            acc[tt] = fmaf(wv.x, xv.x, acc[tt]);
            acc[tt] = fmaf(wv.y, xv.y, acc[tt]);
            acc[tt] = fmaf(wv.z, xv.z, acc[tt]);
            acc[tt] = fmaf(wv.w, xv.w, acc[tt]);
        }
    }
#pragma unroll
    for (int tt = 0; tt < TT; tt++)
        ig[(size_t)(t0 + tt) * H3 + j] = acc[tt];
}

// ---------------------------------------------------------------------------
// Kernel B (sequential scan): one workgroup, 256 threads = 4 waves (1/SIMD).
// tid -> g = tid>>2 (0..63), kseg = tid&3 (32-wide k slice).
// Each thread owns TWO hidden units: g and g+64, i.e. SIX w_hh rows
// {g, g+128, g+256} and {g+64, g+192, g+320}.
//
// WHY 256 threads (R10 lesson): the scan is LDS-BANDWIDTH-bound, not
// VALU-bound. At 512 threads each h value was read by 128 threads ->
// 64 KiB of ds_read_b128 per step (~520-770 cyc of LDS pipe at the
// measured ~85-128 B/cyc). Halving the thread count (doubling rows per
// thread) halves LDS traffic to 32 KiB/step while the VALU issue per
// SIMD is unchanged (1 wave x 192 fma = same 384 cyc, masked-work total
// identical). R10 also showed AGPR-resident weights are read directly
// by VALU (no accvgpr_read tax), so 192 weight floats/thread is fine
// under waves_per_eu(1,1) (512 unified regs).
//
// *** NUMERICS ARE FROZEN (R7/R8 lesson) ***
// 65536-step chaotic recurrence; packed v_pk_fma_f32 failed twice at
// 0.28125. Per-row arithmetic here is VERBATIM the passing form:
// scalar fmaf over K=32 slices per kseg, float4 accumulators,
// (x+y)+(z+w), quad_sum DPP over kseg 0..3. The retiling only changes
// WHICH thread computes a row, not its reduction tree -> h trajectory
// is bit-identical. DO NOT TOUCH THE ARITHMETIC.
//
// Retained levers: depth-2 prefetch, two register sets, no rotation;
// incremental prefetch pointers; raw "lgkmcnt(0); s_barrier" (keeps
// global loads in flight); padded h layout (0 bank conflicts).
// ---------------------------------------------------------------------------
__device__ __forceinline__ void fma4(float4& acc, const float4& wv, const float4& hv)
{
    acc.x = fmaf(wv.x, hv.x, acc.x);
    acc.y = fmaf(wv.y, hv.y, acc.y);
    acc.z = fmaf(wv.z, hv.z, acc.z);
    acc.w = fmaf(wv.w, hv.w, acc.w);
}

__device__ __forceinline__ float quad_sum(float x)
{
    float t;
    t = __int_as_float(__builtin_amdgcn_mov_dpp(__float_as_int(x), 0xB1, 0xF, 0xF, true)); // [1,0,3,2]
    x += t;
    t = __int_as_float(__builtin_amdgcn_mov_dpp(__float_as_int(x), 0x4E, 0xF, 0xF, true)); // [2,3,0,1]
    x += t;
    return x;
}

__device__ __forceinline__ void fast_barrier()
{
    asm volatile("s_waitcnt lgkmcnt(0)\n\ts_barrier" ::: "memory");
}

__device__ __forceinline__ float gru_gate(float c0, float c1, float c2,
                                          float s0, float s1, float s2,
                                          float bn, float hprev)
{
    float er = __expf(-(c0 + s0));
    float r = __builtin_amdgcn_rcpf(1.f + er);
    float ez = __expf(-(c1 + s1));
    float z = __builtin_amdgcn_rcpf(1.f + ez);
    float xn = c2 + r * (s2 + bn);
    float e2 = __expf(-2.f * fabsf(xn));
    float th = (1.f - e2) * __builtin_amdgcn_rcpf(1.f + e2);
    float nn = copysignf(th, xn);
    return nn + z * (hprev - nn);
}

#define HPAD 36  // 32 floats per k-segment + 4 pad

__global__
__attribute__((amdgpu_flat_work_group_size(256, 256), amdgpu_waves_per_eu(1, 1)))
void scan_kernel(const float* __restrict__ ig, const float* __restrict__ h0,
                 const float* __restrict__ w_hh, const float* __restrict__ b_n,
                 float* __restrict__ hlin, int T)
{
    __shared__ __align__(16) float hs[4 * HPAD];

    const int tid = threadIdx.x;     // 0..255
    const int g = tid >> 2;          // 0..63 (unit pair: g and g+64)
    const int kseg = tid & 3;        // 0..3
    const bool gate_lane = (kseg == 0);

    // weights for 6 rows (k slice kseg*32..+32) -> registers (literal idx)
    float4 wA0[8], wA1[8], wA2[8], wB0[8], wB1[8], wB2[8];
    {
        const float* bA0 = w_hh + (size_t)g * HID + kseg * 32;
        const float* bA1 = w_hh + (size_t)(g + HID) * HID + kseg * 32;
        const float* bA2 = w_hh + (size_t)(g + 2 * HID) * HID + kseg * 32;
        const float* bB0 = w_hh + (size_t)(g + 64) * HID + kseg * 32;
        const float* bB1 = w_hh + (size_t)(g + 64 + HID) * HID + kseg * 32;
        const float* bB2 = w_hh + (size_t)(g + 64 + 2 * HID) * HID + kseg * 32;
#pragma unroll
        for (int k = 0; k < 8; k++) {
            wA0[k] = ((const float4*)bA0)[k];
            wA1[k] = ((const float4*)bA1)[k];
            wA2[k] = ((const float4*)bA2)[k];
            wB0[k] = ((const float4*)bB0)[k];
            wB1[k] = ((const float4*)bB1)[k];
            wB2[k] = ((const float4*)bB2)[k];
        }
    }
    if (tid < HID) hs[(tid >> 5) * HPAD + (tid & 31)] = h0[tid];

    // gate inputs: units A=g, B=g+64; sets 0 (even step) / 1 (odd step)
    float bnA = 0.f, bnB = 0.f;
    float pA00 = 0.f, pA01 = 0.f, pA02 = 0.f, pA10 = 0.f, pA11 = 0.f, pA12 = 0.f;
    float pB00 = 0.f, pB01 = 0.f, pB02 = 0.f, pB10 = 0.f, pB11 = 0.f, pB12 = 0.f;
    if (gate_lane) {
        bnA = b_n[g];
        bnB = b_n[g + 64];
        pA00 = ig[g];            pB00 = ig[g + 64];
        pA01 = ig[HID + g];      pB01 = ig[HID + g + 64];
        pA02 = ig[2 * HID + g];  pB02 = ig[2 * HID + g + 64];
        const float* q = ig + H3;
        pA10 = q[g];             pB10 = q[g + 64];
        pA11 = q[HID + g];       pB11 = q[HID + g + 64];
        pA12 = q[2 * HID + g];   pB12 = q[2 * HID + g + 64];
    }
    __syncthreads();

    const float4* hp = (const float4*)(hs + kseg * HPAD);
    const int hwA = (g >> 5) * HPAD + (g & 31);  // unit g slot
    const int hwB = hwA + 2 * HPAD;              // unit g+64 slot

    // incrementally-advanced prefetch bases: ig[(s+2)*H3 + ...]
    const float* pfA = ig + (size_t)2 * H3 + g;
    const float* pfB = pfA + 64;
    float* hl = hlin + g;  // hlin[step*LIN_IN + g], advanced by LIN_IN

#define MATVEC_GATES(A0, A1, A2, B0, B1, B2, DO_PREFETCH)                      \
    {                                                                          \
        float hprevA = 0.f, hprevB = 0.f;                                      \
        if (gate_lane) { hprevA = hs[hwA]; hprevB = hs[hwB]; }                 \
        float4 aA0 = {0.f, 0.f, 0.f, 0.f}, aA1 = aA0, aA2 = aA0;               \
        float4 aB0 = aA0, aB1 = aA0, aB2 = aA0;                                \
        _Pragma("unroll")                                                      \
        for (int kk = 0; kk < 8; kk++) {                                       \
            float4 hv = hp[kk];                                                \
            fma4(aA0, wA0[kk], hv);                                            \
            fma4(aA1, wA1[kk], hv);                                            \
            fma4(aA2, wA2[kk], hv);                                            \
            fma4(aB0, wB0[kk], hv);                                            \
            fma4(aB1, wB1[kk], hv);                                            \
            fma4(aB2, wB2[kk], hv);                                            \
        }                                                                      \
        float sA0 = (aA0.x + aA0.y) + (aA0.z + aA0.w);                         \
        float sA1 = (aA1.x + aA1.y) + (aA1.z + aA1.w);                         \
        float sA2 = (aA2.x + aA2.y) + (aA2.z + aA2.w);                         \
        float sB0 = (aB0.x + aB0.y) + (aB0.z + aB0.w);                         \
        float sB1 = (aB1.x + aB1.y) + (aB1.z + aB1.w);                         \
        float sB2 = (aB2.x + aB2.y) + (aB2.z + aB2.w);                         \
        sA0 = quad_sum(sA0); sA1 = quad_sum(sA1); sA2 = quad_sum(sA2);         \
        sB0 = quad_sum(sB0); sB1 = quad_sum(sB1); sB2 = quad_sum(sB2);         \
        if (gate_lane) {                                                       \
            float hnewA = gru_gate(A0, A1, A2, sA0, sA1, sA2, bnA, hprevA);    \
            float hnewB = gru_gate(B0, B1, B2, sB0, sB1, sB2, bnB, hprevB);    \
            hs[hwA] = hnewA;                                                   \
            hs[hwB] = hnewB;                                                   \
            if (g < LIN_IN) *hl = hnewA;                                       \
            if (DO_PREFETCH) {  /* refill this set for step+2 */               \
                A0 = pfA[0];                                                   \
                A1 = pfA[HID];                                                 \
                A2 = pfA[2 * HID];                                             \
                B0 = pfB[0];                                                   \
                B1 = pfB[HID];                                                 \
                B2 = pfB[2 * HID];                                             \
            }                                                                  \
        }                                                                      \
        hl += LIN_IN;                                                          \
        pfA += H3;                                                             \
        pfB += H3;                                                             \
        fast_barrier();                                                        \
    }

    int s = 0;
    for (; s + 4 <= T; s += 2) {           // both halves may prefetch
        MATVEC_GATES(pA00, pA01, pA02, pB00, pB01, pB02, true)
        MATVEC_GATES(pA10, pA11, pA12, pB10, pB11, pB12, true)
    }
    // tail: last two steps, no prefetch (uniform, outside the hot loop)
    MATVEC_GATES(pA00, pA01, pA02, pB00, pB01, pB02, false)
    MATVEC_GATES(pA10, pA11, pA12, pB10, pB11, pB12, false)
#undef MATVEC_GATES
}

// ---------------------------------------------------------------------------
// Kernel C (parallel): out[t] = dot(hlin[t,:], xlin[t,:]) + lbias
// ---------------------------------------------------------------------------
__global__ __launch_bounds__(256)
void readout_kernel(const float* __restrict__ hlin, const float* __restrict__ xlin,
                    const float* __restrict__ lbias, float* __restrict__ out, int T)
{
    int gid = blockIdx.x * 256 + threadIdx.x;
    int t = gid >> 3;
    int seg = gid & 7;
    if (t < T) {
        float4 hv = ((const float4*)hlin)[(size_t)t * 8 + seg];
        float4 xv = ((const float4*)xlin)[(size_t)t * 8 + seg];
        float p = hv.x * xv.x + hv.y * xv.y + hv.z * xv.z + hv.w * xv.w;
        p += __shfl_xor(p, 1);
        p += __shfl_xor(p, 2);
        p += __shfl_xor(p, 4);
        if (seg == 0) out[t] = p + lbias[0];
    }
}

extern "C" void kernel_launch(void* const* d_in, const int* in_sizes, int n_in,
                              void* d_out, int out_size, void* d_ws, size_t ws_size,
                              hipStream_t stream) {
    const float* x_gru = (const float*)d_in[0];  // (T, 96)
    const float* x_lin = (const float*)d_in[1];  // (T, 32)
    const float* h0    = (const float*)d_in[2];  // (128,)
    const float* w_ih  = (const float*)d_in[3];  // (384, 96)
    const float* w_hh  = (const float*)d_in[4];  // (384, 128)
    const float* b_ih  = (const float*)d_in[5];  // (384,)
    const float* b_n   = (const float*)d_in[6];  // (128,)
    const float* lbias = (const float*)d_in[7];  // (1,)
    float* out = (float*)d_out;                  // (T, 1)

    int T = in_sizes[0] / IN_SIZE;               // 65536 (even)
    float* igates = (float*)d_ws;                    // T*384 floats = 96 MiB
    float* hlin   = (float*)d_ws + (size_t)T * H3;   // T*32 floats  =  8 MiB

    igates_kernel<<<T / 16, 384, 0, stream>>>(x_gru, w_ih, b_ih, igates, T);
    scan_kernel<<<1, 256, 0, stream>>>(igates, h0, w_hh, b_n, hlin, T);
    readout_kernel<<<(T * 8 + 255) / 256, 256, 0, stream>>>(hlin, x_lin, lbias, out, T);
}